// Round 4
// baseline (1403.005 us; speedup 1.0000x reference)
//
#include <hip/hip_runtime.h>
#include <math.h>
#include <stdint.h>
#include <stddef.h>

typedef short short8 __attribute__((ext_vector_type(8)));   // 8 x bf16 fragment
typedef float f32x4 __attribute__((ext_vector_type(4)));

#define NKT 24           // 768 / 32 K-tiles
#define ROWPB 80         // LDS tile row stride: 64 B real (32 bf16) + 16 B pad

// DCT basis (P=3): rows {CA,CA,CA},{CB,0,-CB},{CC,CD,CC}
#define CA 0.57735026918962576f
#define CB 0.70710678118654752f
#define CC 0.40824829046386302f
#define CD -0.81649658092772603f

#define LDS_A 0u                 // 144 rows * 80 B = 11520 B
#define LDS_B 11520u             // 256 rows * 80 B = 20480 B  (GEMM uses 32000 B)
#define LDS_TOTAL 73728          // epilogue scratch 8 waves * 9216 B dominates

// f32 -> bf16 round-to-nearest-even (inputs are finite; no NaN path needed)
static __device__ __forceinline__ unsigned short f2bf(float x) {
  union { float f; unsigned u; } v; v.f = x;
  unsigned r = v.u + 0x7fffu + ((v.u >> 16) & 1u);
  return (unsigned short)(r >> 16);
}

// ---------------------------------------------------------------------------
// Single fused kernel, zero workspace, conservative schedule.
//   C-tile 144x256 per block (BM=144 = 16 windows * 9, BN=256, BK=32).
//   8 waves; wave wv owns cols [wv*32, wv*32+32) x all 144 rows.
//   A-tile: on-the-fly edge-clamped 3x3 window DCT -> bf16 LDS.
//   B-tile: on-the-fly f32->bf16 convert of W1 rows -> bf16 LDS.
//   Verified MFMA pattern (m92): A row=lane&15, k=(lane>>4)*8+j;
//   C/D: col=lane&15, row=(lane>>4)*4+reg.
//   Epilogue: bias + exact GELU -> per-wave LDS scratch -> 2D IDCT -> crop,
//   with a finite-guard sentinel (non-finite -> 1e6) making failures readable.
// ---------------------------------------------------------------------------
__global__ __launch_bounds__(512, 2) void fused_kernel(
    const float* __restrict__ f, const float* __restrict__ W1,
    const float* __restrict__ b1, float* __restrict__ out) {
  __shared__ alignas(16) unsigned char smem[LDS_TOTAL];

  const int bid = blockIdx.x;
  const int mt = bid / 3;
  const int nt = bid - mt * 3;
  const int n0 = nt * 256;
  const int tid = threadIdx.x;
  const int wv = tid >> 6;
  const int lane = tid & 63;
  const int lrow = lane & 15;        // C col within 16-col fragment
  const int kgrp = lane >> 4;        // 0..3

  const float Cm[3][3] = {{CA, CA, CA}, {CB, 0.f, -CB}, {CC, CD, CC}};

  // ---- A-staging geometry: thread = (window aw=tid>>5, feature ak=tid&31) ----
  const int aw = tid >> 5;
  const int ak = tid & 31;
  const int gwin = mt * 16 + aw;                 // 0..7743
  const int ab2 = gwin / 484;                    // image 0..15
  const int arem = gwin - ab2 * 484;
  const int abh = arem / 22;
  const int abw = arem - abh * 22;
  const float* fp[9];
#pragma unroll
  for (int p = 0; p < 3; ++p) {
    int h = abh * 3 + p; h = h > 63 ? 63 : h;    // edge padding == index clamp
#pragma unroll
    for (int q = 0; q < 3; ++q) {
      int w = abw * 3 + q; w = w > 63 ? 63 : w;
      fp[p * 3 + q] = f + ((((size_t)ab2 * 64 + h) * 64 + w) * 768 + ak);
    }
  }
  const unsigned abase0 = LDS_A + (unsigned)(aw * 9) * ROWPB + (unsigned)ak * 2;

  // ---- B-staging geometry: thread = (row bn=tid>>1, 16-float half bh_) ----
  const int bn = tid >> 1;
  const int bh_ = tid & 1;
  const float* gW = W1 + (size_t)(n0 + bn) * 768 + bh_ * 16;
  const unsigned bwr = LDS_B + (unsigned)bn * ROWPB + (unsigned)bh_ * 32;

  f32x4 acc[9][2];
#pragma unroll
  for (int i = 0; i < 9; ++i) {
    acc[i][0] = (f32x4){0.f, 0.f, 0.f, 0.f};
    acc[i][1] = (f32x4){0.f, 0.f, 0.f, 0.f};
  }

  float xr[9];
  f32x4 wr[4];
  auto loadF = [&](int kt) {
    const int off = kt * 32;
#pragma unroll
    for (int i = 0; i < 9; ++i) xr[i] = fp[i][off];
  };
  auto loadB = [&](int kt) {
    const float* p = gW + kt * 32;
#pragma unroll
    for (int i = 0; i < 4; ++i) wr[i] = *(const f32x4*)(p + i * 4);
  };
  auto dctWriteA = [&]() {
    float s1[3][3];
#pragma unroll
    for (int p = 0; p < 3; ++p)
#pragma unroll
      for (int c = 0; c < 3; ++c)
        s1[p][c] = Cm[c][0] * xr[p * 3] + Cm[c][1] * xr[p * 3 + 1] + Cm[c][2] * xr[p * 3 + 2];
#pragma unroll
    for (int a = 0; a < 3; ++a)
#pragma unroll
      for (int c = 0; c < 3; ++c) {
        float t = Cm[a][0] * s1[0][c] + Cm[a][1] * s1[1][c] + Cm[a][2] * s1[2][c];
        *(unsigned short*)(smem + abase0 + (unsigned)(a * 3 + c) * ROWPB) = f2bf(t);
      }
  };
  auto writeB = [&]() {
    short8 s0, s1v;
#pragma unroll
    for (int i = 0; i < 4; ++i) {
      s0[i]     = (short)f2bf(wr[0][i]);
      s0[i + 4] = (short)f2bf(wr[1][i]);
      s1v[i]     = (short)f2bf(wr[2][i]);
      s1v[i + 4] = (short)f2bf(wr[3][i]);
    }
    *(short8*)(smem + bwr)      = s0;
    *(short8*)(smem + bwr + 16) = s1v;
  };

  // fragment byte offsets (80 B rows: 16-B aligned, benign bank aliasing)
  const unsigned aoff = LDS_A + (unsigned)lrow * ROWPB + (unsigned)kgrp * 16;
  const unsigned boff = LDS_B + (unsigned)(wv * 32 + lrow) * ROWPB + (unsigned)kgrp * 16;

  loadF(0);
  loadB(0);

  for (int kt = 0; kt < NKT; ++kt) {
    __syncthreads();               // all waves done READING previous tile
    dctWriteA();                   // write tile kt (regs loaded last iter)
    writeB();
    __syncthreads();               // writes visible to all waves
    if (kt + 1 < NKT) {            // register-only prefetch; no LDS hazard
      loadF(kt + 1);
      loadB(kt + 1);
    }
    short8 bf0 = *(const short8*)(smem + boff);
    short8 bf1 = *(const short8*)(smem + boff + 16u * ROWPB);
#pragma unroll
    for (int rf = 0; rf < 9; ++rf) {
      short8 af = *(const short8*)(smem + aoff + (unsigned)rf * (16u * ROWPB));
      acc[rf][0] = __builtin_amdgcn_mfma_f32_16x16x32_bf16(af, bf0, acc[rf][0], 0, 0, 0);
      acc[rf][1] = __builtin_amdgcn_mfma_f32_16x16x32_bf16(af, bf1, acc[rf][1], 0, 0, 0);
    }
  }

  __syncthreads();                 // MFMA reads done before smem is repurposed

  // ---- epilogue: bias + exact GELU -> per-wave scratch -> 2D IDCT -> store ----
  float* ep = (float*)(smem + wv * 9216);   // 144 x 16 f32 per wave

#pragma unroll 1
  for (int cf = 0; cf < 2; ++cf) {
    const int colg = n0 + wv * 32 + cf * 16 + lrow;
    const float bias = b1[colg];
#pragma unroll
    for (int rf = 0; rf < 9; ++rf) {
#pragma unroll
      for (int j = 0; j < 4; ++j) {
        const int row = rf * 16 + kgrp * 4 + j;   // C/D: row=(lane>>4)*4+reg
        float v = acc[rf][cf][j] + bias;
        float g = 0.5f * v * (1.0f + erff(v * 0.70710678118654752f));
        ep[row * 16 + lrow] = g;
      }
    }
    __syncthreads();               // ordering insurance (uniform for all waves)
#pragma unroll
    for (int it = 0; it < 4; ++it) {
      const int w = it * 4 + kgrp;          // window within tile (0..15)
      const int gw = mt * 16 + w;
      const int bb2 = gw / 484;
      const int rem = gw - bb2 * 484;
      const int bh = rem / 22;
      const int bw = rem - bh * 22;
      float y[3][3];
#pragma unroll
      for (int a = 0; a < 3; ++a)
#pragma unroll
        for (int c = 0; c < 3; ++c)
          y[a][c] = ep[(w * 9 + a * 3 + c) * 16 + lrow];
      float vt[3][3];
#pragma unroll
      for (int a = 0; a < 3; ++a)
#pragma unroll
        for (int q = 0; q < 3; ++q)
          vt[a][q] = y[a][0] * Cm[0][q] + y[a][1] * Cm[1][q] + y[a][2] * Cm[2][q];
#pragma unroll
      for (int p = 0; p < 3; ++p) {
        const int h = bh * 3 + p;
        if (h >= 64) continue;              // crop padded rows
#pragma unroll
        for (int q = 0; q < 3; ++q) {
          const int ww = bw * 3 + q;
          if (ww >= 64) continue;           // crop padded cols
          float o = Cm[0][p] * vt[0][q] + Cm[1][p] * vt[1][q] + Cm[2][p] * vt[2][q];
          // Diagnostic sentinel: output can never be NaN; a 1e6 absmax means
          // a non-finite value reached the epilogue (staging/MFMA problem).
          if (!__builtin_isfinite(o)) o = 1.0e6f;
          out[(((size_t)bb2 * 64 + h) * 64 + ww) * 768 + colg] = o;
        }
      }
    }
    __syncthreads();               // reads done before cf=1 overwrites ep
  }
}

// ---------------------------------------------------------------------------
extern "C" void kernel_launch(void* const* d_in, const int* in_sizes, int n_in,
                              void* d_out, int out_size, void* d_ws, size_t ws_size,
                              hipStream_t stream) {
  const float* f  = (const float*)d_in[0];
  const float* W1 = (const float*)d_in[1];
  const float* b1 = (const float*)d_in[2];
  float* out = (float*)d_out;
  (void)d_ws; (void)ws_size;   // zero-workspace design

  fused_kernel<<<dim3(484 * 3), dim3(512), 0, stream>>>(f, W1, b1, out);
}

// Round 5
// 385.008 us; speedup vs baseline: 3.6441x; 3.6441x over previous
//
#include <hip/hip_runtime.h>
#include <math.h>
#include <stdint.h>
#include <stddef.h>

typedef short short8 __attribute__((ext_vector_type(8)));   // 8 x bf16 fragment
typedef float f32x4 __attribute__((ext_vector_type(4)));

#define NKT 24           // 768 / 32 K-tiles
#define ROWPB 80         // LDS tile row stride: 64 B real (32 bf16) + 16 B pad

// DCT basis (P=3): rows {CA,CA,CA},{CB,0,-CB},{CC,CD,CC}
#define CA 0.57735026918962576f
#define CB 0.70710678118654752f
#define CC 0.40824829046386302f
#define CD -0.81649658092772603f

#define LDS_A 0u                 // 144 rows * 80 B = 11520 B
#define LDS_B 11520u             // 256 rows * 80 B = 20480 B  (GEMM uses 32000 B)
#define LDS_TOTAL 73728          // epilogue: [72][256] f32 = 73728 B exactly

// f32 -> bf16 round-to-nearest-even
static __device__ __forceinline__ unsigned short f2bf(float x) {
  union { float f; unsigned u; } v; v.f = x;
  unsigned r = v.u + 0x7fffu + ((v.u >> 16) & 1u);
  return (unsigned short)(r >> 16);
}

// ---------------------------------------------------------------------------
// Single fused kernel, zero workspace.
//   GEMM core: identical to the R4-verified structure (bf16 MFMA 16x16x32,
//   BM=144, BN=256, BK=32, single-buffered LDS, 2 barriers/K-step, register
//   prefetch of next tile's globals).
//   NEW epilogue (R5): two window-half passes; GELU results staged in a
//   shared [72][256] f32 LDS tile; each wave then IDCTs one window and emits
//   64-lane contiguous 256 B nontemporal stores -> every 128 B out line
//   written exactly once (kills the 27x write amplification seen in R4).
// ---------------------------------------------------------------------------
__global__ __launch_bounds__(512, 2) void fused_kernel(
    const float* __restrict__ f, const float* __restrict__ W1,
    const float* __restrict__ b1, float* __restrict__ out) {
  __shared__ alignas(16) unsigned char smem[LDS_TOTAL];

  const int bid = blockIdx.x;
  const int mt = bid / 3;
  const int nt = bid - mt * 3;
  const int n0 = nt * 256;
  const int tid = threadIdx.x;
  const int wv = tid >> 6;
  const int lane = tid & 63;
  const int lrow = lane & 15;        // C col within 16-col fragment
  const int kgrp = lane >> 4;        // 0..3

  const float Cm[3][3] = {{CA, CA, CA}, {CB, 0.f, -CB}, {CC, CD, CC}};

  // ---- A-staging geometry: thread = (window aw=tid>>5, feature ak=tid&31) ----
  const int aw = tid >> 5;
  const int ak = tid & 31;
  const int gwin = mt * 16 + aw;                 // 0..7743
  const int ab2 = gwin / 484;                    // image 0..15
  const int arem = gwin - ab2 * 484;
  const int abh = arem / 22;
  const int abw = arem - abh * 22;
  const float* fp[9];
#pragma unroll
  for (int p = 0; p < 3; ++p) {
    int h = abh * 3 + p; h = h > 63 ? 63 : h;    // edge padding == index clamp
#pragma unroll
    for (int q = 0; q < 3; ++q) {
      int w = abw * 3 + q; w = w > 63 ? 63 : w;
      fp[p * 3 + q] = f + ((((size_t)ab2 * 64 + h) * 64 + w) * 768 + ak);
    }
  }
  const unsigned abase0 = LDS_A + (unsigned)(aw * 9) * ROWPB + (unsigned)ak * 2;

  // ---- B-staging geometry: thread = (row bn=tid>>1, 16-float half bh_) ----
  const int bn = tid >> 1;
  const int bh_ = tid & 1;
  const float* gW = W1 + (size_t)(n0 + bn) * 768 + bh_ * 16;
  const unsigned bwr = LDS_B + (unsigned)bn * ROWPB + (unsigned)bh_ * 32;

  f32x4 acc[9][2];
#pragma unroll
  for (int i = 0; i < 9; ++i) {
    acc[i][0] = (f32x4){0.f, 0.f, 0.f, 0.f};
    acc[i][1] = (f32x4){0.f, 0.f, 0.f, 0.f};
  }

  float xr[9];
  f32x4 wr[4];
  auto loadF = [&](int kt) {
    const int off = kt * 32;
#pragma unroll
    for (int i = 0; i < 9; ++i) xr[i] = fp[i][off];
  };
  auto loadB = [&](int kt) {
    const float* p = gW + kt * 32;
#pragma unroll
    for (int i = 0; i < 4; ++i) wr[i] = *(const f32x4*)(p + i * 4);
  };
  auto dctWriteA = [&]() {
    float s1[3][3];
#pragma unroll
    for (int p = 0; p < 3; ++p)
#pragma unroll
      for (int c = 0; c < 3; ++c)
        s1[p][c] = Cm[c][0] * xr[p * 3] + Cm[c][1] * xr[p * 3 + 1] + Cm[c][2] * xr[p * 3 + 2];
#pragma unroll
    for (int a = 0; a < 3; ++a)
#pragma unroll
      for (int c = 0; c < 3; ++c) {
        float t = Cm[a][0] * s1[0][c] + Cm[a][1] * s1[1][c] + Cm[a][2] * s1[2][c];
        *(unsigned short*)(smem + abase0 + (unsigned)(a * 3 + c) * ROWPB) = f2bf(t);
      }
  };
  auto writeB = [&]() {
    short8 s0, s1v;
#pragma unroll
    for (int i = 0; i < 4; ++i) {
      s0[i]     = (short)f2bf(wr[0][i]);
      s0[i + 4] = (short)f2bf(wr[1][i]);
      s1v[i]     = (short)f2bf(wr[2][i]);
      s1v[i + 4] = (short)f2bf(wr[3][i]);
    }
    *(short8*)(smem + bwr)      = s0;
    *(short8*)(smem + bwr + 16) = s1v;
  };

  const unsigned aoff = LDS_A + (unsigned)lrow * ROWPB + (unsigned)kgrp * 16;
  const unsigned boff = LDS_B + (unsigned)(wv * 32 + lrow) * ROWPB + (unsigned)kgrp * 16;

  loadF(0);
  loadB(0);

  for (int kt = 0; kt < NKT; ++kt) {
    __syncthreads();               // all waves done READING previous tile
    dctWriteA();                   // write tile kt (regs loaded last iter)
    writeB();
    __syncthreads();               // writes visible to all waves
    if (kt + 1 < NKT) {            // register-only prefetch; no LDS hazard
      loadF(kt + 1);
      loadB(kt + 1);
    }
    short8 bf0 = *(const short8*)(smem + boff);
    short8 bf1 = *(const short8*)(smem + boff + 16u * ROWPB);
#pragma unroll
    for (int rf = 0; rf < 9; ++rf) {
      short8 af = *(const short8*)(smem + aoff + (unsigned)rf * (16u * ROWPB));
      acc[rf][0] = __builtin_amdgcn_mfma_f32_16x16x32_bf16(af, bf0, acc[rf][0], 0, 0, 0);
      acc[rf][1] = __builtin_amdgcn_mfma_f32_16x16x32_bf16(af, bf1, acc[rf][1], 0, 0, 0);
    }
  }

  // ---- epilogue: two window-half passes over a shared [72][256] tile ----
  float* ep2 = (float*)smem;
  const float bias0 = b1[n0 + wv * 32 + lrow];
  const float bias1 = b1[n0 + wv * 32 + 16 + lrow];

#pragma unroll 1
  for (int hs = 0; hs < 2; ++hs) {
    __syncthreads();               // previous readers of smem are done
    // (1) GELU -> ep2 for M-rows [hs*72, hs*72+72), this wave's 32 cols
#pragma unroll
    for (int cf = 0; cf < 2; ++cf) {
      const float bias = cf ? bias1 : bias0;
      const int colE = wv * 32 + cf * 16 + lrow;
#pragma unroll
      for (int rf = 0; rf < 9; ++rf) {
#pragma unroll
        for (int j = 0; j < 4; ++j) {
          const int r = rf * 16 + kgrp * 4 + j;   // C/D: row=(lane>>4)*4+reg
          const int lr = r - hs * 72;
          if (lr >= 0 && lr < 72) {
            float v = acc[rf][cf][j] + bias;
            float g = 0.5f * v * (1.0f + erff(v * 0.70710678118654752f));
            ep2[lr * 256 + colE] = g;
          }
        }
      }
    }
    __syncthreads();
    // (2) wave wv IDCTs window hs*8+wv; 256 B contiguous NT stores
    const int gw = mt * 16 + hs * 8 + wv;
    const int ib = gw / 484;
    const int rem = gw - ib * 484;
    const int bh = rem / 22;
    const int bw = rem - bh * 22;
    const float* epw = ep2 + wv * 9 * 256;
#pragma unroll
    for (int ch = 0; ch < 4; ++ch) {
      const int col = ch * 64 + lane;
      float y[3][3];
#pragma unroll
      for (int a = 0; a < 3; ++a)
#pragma unroll
        for (int c = 0; c < 3; ++c)
          y[a][c] = epw[(a * 3 + c) * 256 + col];
      float vt[3][3];                 // vt[a][q] = sum_c y[a][c] * Cm[c][q]
#pragma unroll
      for (int a = 0; a < 3; ++a)
#pragma unroll
        for (int q = 0; q < 3; ++q)
          vt[a][q] = y[a][0] * Cm[0][q] + y[a][1] * Cm[1][q] + y[a][2] * Cm[2][q];
#pragma unroll
      for (int p = 0; p < 3; ++p) {
        const int h = bh * 3 + p;
        if (h >= 64) continue;        // crop (uniform per wave)
#pragma unroll
        for (int q = 0; q < 3; ++q) {
          const int ww = bw * 3 + q;
          if (ww >= 64) continue;     // crop (uniform per wave)
          const float o = Cm[0][p] * vt[0][q] + Cm[1][p] * vt[1][q] + Cm[2][p] * vt[2][q];
          __builtin_nontemporal_store(
              o, out + ((((size_t)ib * 64 + h) * 64 + ww) * 768 + n0 + col));
        }
      }
    }
  }
}

// ---------------------------------------------------------------------------
extern "C" void kernel_launch(void* const* d_in, const int* in_sizes, int n_in,
                              void* d_out, int out_size, void* d_ws, size_t ws_size,
                              hipStream_t stream) {
  const float* f  = (const float*)d_in[0];
  const float* W1 = (const float*)d_in[1];
  const float* b1 = (const float*)d_in[2];
  float* out = (float*)d_out;
  (void)d_ws; (void)ws_size;   // zero-workspace design

  fused_kernel<<<dim3(484 * 3), dim3(512), 0, stream>>>(f, W1, b1, out);
}